// Round 9
// baseline (77175.592 us; speedup 1.0000x reference)
//
#include <hip/hip_runtime.h>
#include <hip/hip_cooperative_groups.h>
#include <math.h>

namespace cg = cooperative_groups;

#define BB 128   // batch
#define TT 256   // time
#define DD 256   // input dims
#define UU 512   // units
#define RR 512   // ladder order

// ---- coop ws layout (floats): transposed activations [col][row] ----
#define OFF_XT0 0          // x ping  [512][128]
#define OFF_XT1 65536      // x pong
#define OFF_HT0 131072     // h ping  [512][128]
#define OFF_HT1 196608     // h pong
#define OFF_MT  262144     // m_t     [256][128]
#define OFF_MR  294912     // m_t row-major [128][256] (for u staging)
#define WS_FLT  327680
#define WS_NEED_BYTES (WS_FLT * 4)   // 1,310,720 B (== round-5-verified bound)

// ---- LDS layout (floats), dynamic, per role ----
#define LA  0        // x: AT slice [512][4]
#define LB  2048     // x: BT slice [256][4]
#define LC  3072     // x(m-role): CT slice [512][4]
#define LU  5120     // x: u chunk [128][129] (pad 129 -> conflict-free both ways)
#define LWH 0        // h: WyhT slice [512][4]
#define LWX 2048     // h: WyxT slice [512][4]
#define LWF 4096     // h: WyfT slice [256][4]
#define LFM 5120     // h: wfm[256]
#define LDS_FLT 21632
#define LDS_BYTES (LDS_FLT * 4)      // 86,528 B -> 1 block/CU

// Bitwise contract (matches np reference, proven round 7/8):
//  - every dot = ascending-k single-accumulator fmaf chain from 0.0f
//  - x = accA + accB (one add);  u = inp + m (one add);  f = wfm*m (one mul)
//  - z = ((accH + accX) + accF) + by;  h = tanhf(z)
__global__ __launch_bounds__(256) void ladder_coop(
    const float* __restrict__ inputs, const float* __restrict__ wfm,
    const float* __restrict__ by,     const float* __restrict__ WyhT,
    const float* __restrict__ WyxT,   const float* __restrict__ WyfT,
    const float* __restrict__ AT,     const float* __restrict__ BT,
    const float* __restrict__ CT,
    float* __restrict__ ws, float* __restrict__ out)
{
    extern __shared__ float lds[];
    cg::grid_group grid = cg::this_grid();
    const int bid = blockIdx.x;
    const int tid = threadIdx.x;
    // lane map: r = 32-row group per wave-half, cp duplicated across lane>>5
    // -> activation reads merge to one 128B line per 32 lanes (L1 dedup)
    const int r  = ((tid >> 6) << 5) + (tid & 31);   // 0..127
    const int cp = (tid >> 5) & 1;                   // 0..1
    const bool isx = bid < 128;

    // ---- one-time: stage this block's weight slices into LDS ----
    if (isx) {
        const int C0 = bid * 4;
        for (int i = tid; i < 2048; i += 256) {
            int k = i >> 2, ci = i & 3;
            lds[LA + i] = AT[k * RR + C0 + ci];
        }
        for (int i = tid; i < 1024; i += 256) {
            int d = i >> 2, ci = i & 3;
            lds[LB + i] = BT[d * RR + C0 + ci];
        }
        if (bid < 64) {
            const int M0 = bid * 4;
            for (int i = tid; i < 2048; i += 256) {
                int k = i >> 2, ci = i & 3;
                lds[LC + i] = CT[k * DD + M0 + ci];
            }
        }
    } else {
        const int C0 = (bid - 128) * 4;
        for (int i = tid; i < 2048; i += 256) {
            int k = i >> 2, ci = i & 3;
            lds[LWH + i] = WyhT[k * UU + C0 + ci];
            lds[LWX + i] = WyxT[k * UU + C0 + ci];
        }
        for (int i = tid; i < 1024; i += 256) {
            int d = i >> 2, ci = i & 3;
            lds[LWF + i] = WyfT[d * UU + C0 + ci];
        }
        for (int i = tid; i < 256; i += 256)
            lds[LFM + i] = wfm[i];
    }
    // ---- zero ws (x_{-1}, h_{-1}, m_{-1} must be exact 0) ----
    for (int i = bid * 256 + tid; i < WS_FLT; i += 65536)
        ws[i] = 0.0f;
    __syncthreads();
    grid.sync();

    // ================= x_{tin} computation =================
    auto do_x = [&](int tin) {
        const int C0 = bid * 4;
        const int ca = C0 + cp * 2;
        const float* Xp = ws + ((tin & 1) ? OFF_XT0 : OFF_XT1);  // x_{tin-1}
        float*       Xn = ws + ((tin & 1) ? OFF_XT1 : OFF_XT0);  // x_tin
        float a0 = 0.0f, a1 = 0.0f;
        #pragma unroll 8
        for (int k = 0; k < RR; ++k) {
            float xv = Xp[k * 128 + r];
            a0 = fmaf(xv, lds[LA + k * 4 + cp * 2], a0);
            a1 = fmaf(xv, lds[LA + k * 4 + cp * 2 + 1], a1);
        }
        float b0 = 0.0f, b1 = 0.0f;
        const int dd = tid & 127, half = tid >> 7;
        for (int ch = 0; ch < 2; ++ch) {
            __syncthreads();
            // stage u = inp_tin + m_{tin-1} for d in [ch*128, ch*128+128)
            {
                const int d = ch * 128 + dd;
                #pragma unroll 4
                for (int j = 0; j < 64; ++j) {
                    int rr = half * 64 + j;
                    float u = inputs[(rr * TT + tin) * DD + d]
                            + ws[OFF_MR + rr * 256 + d];
                    lds[LU + dd * 129 + rr] = u;
                }
            }
            __syncthreads();
            #pragma unroll 8
            for (int dl = 0; dl < 128; ++dl) {
                int d = ch * 128 + dl;
                float uv = lds[LU + dl * 129 + r];
                b0 = fmaf(uv, lds[LB + d * 4 + cp * 2], b0);
                b1 = fmaf(uv, lds[LB + d * 4 + cp * 2 + 1], b1);
            }
        }
        Xn[ca * 128 + r]       = a0 + b0;
        Xn[(ca + 1) * 128 + r] = a1 + b1;
    };

    // ================= main time loop =================
    for (int t = 0; t < TT; ++t) {
        if (t == 0) {           // prologue: x_0 from zeros (bitwise: fmaf(0,w,0)=0)
            if (isx) do_x(0);
            grid.sync();
        }
        // ---- phase A: m_t = x_t @ CT (blocks 0..63) ----
        if (bid < 64) {
            const int ca = bid * 4 + cp * 2;
            const float* X = ws + ((t & 1) ? OFF_XT1 : OFF_XT0);
            float a0 = 0.0f, a1 = 0.0f;
            #pragma unroll 8
            for (int k = 0; k < RR; ++k) {
                float xv = X[k * 128 + r];
                a0 = fmaf(xv, lds[LC + k * 4 + cp * 2], a0);
                a1 = fmaf(xv, lds[LC + k * 4 + cp * 2 + 1], a1);
            }
            ws[OFF_MT + ca * 128 + r]       = a0;
            ws[OFF_MT + (ca + 1) * 128 + r] = a1;
            ws[OFF_MR + r * 256 + ca]       = a0;
            ws[OFF_MR + r * 256 + ca + 1]   = a1;
        }
        grid.sync();
        // ---- phase B: h_t (blocks 128..255)  ||  x_{t+1} (blocks 0..127) ----
        if (!isx) {
            const int C0 = (bid - 128) * 4;
            const int ca = C0 + cp * 2;
            const float* X  = ws + ((t & 1) ? OFF_XT1 : OFF_XT0);  // x_t
            const float* Hp = ws + ((t & 1) ? OFF_HT0 : OFF_HT1);  // h_{t-1}
            float*       Hn = ws + ((t & 1) ? OFF_HT1 : OFF_HT0);  // h_t
            float h0 = 0.0f, h1 = 0.0f, x0 = 0.0f, x1 = 0.0f;
            #pragma unroll 8
            for (int k = 0; k < UU; ++k) {
                float hv = Hp[k * 128 + r];
                float xv = X[k * 128 + r];
                h0 = fmaf(hv, lds[LWH + k * 4 + cp * 2], h0);
                h1 = fmaf(hv, lds[LWH + k * 4 + cp * 2 + 1], h1);
                x0 = fmaf(xv, lds[LWX + k * 4 + cp * 2], x0);
                x1 = fmaf(xv, lds[LWX + k * 4 + cp * 2 + 1], x1);
            }
            float f0 = 0.0f, f1 = 0.0f;
            #pragma unroll 8
            for (int d = 0; d < DD; ++d) {
                float mv = ws[OFF_MT + d * 128 + r];
                float fv = lds[LFM + d] * mv;      // f = wfm*m (one round)
                f0 = fmaf(fv, lds[LWF + d * 4 + cp * 2], f0);
                f1 = fmaf(fv, lds[LWF + d * 4 + cp * 2 + 1], f1);
            }
            float z0 = ((h0 + x0) + f0) + by[ca];
            float z1 = ((h1 + x1) + f1) + by[ca + 1];
            float th0 = tanhf(z0), th1 = tanhf(z1);
            Hn[ca * 128 + r]       = th0;
            Hn[(ca + 1) * 128 + r] = th1;
            out[(r * TT + t) * UU + ca]     = th0;
            out[(r * TT + t) * UU + ca + 1] = th1;
        } else if (t < TT - 1) {
            do_x(t + 1);
        }
        grid.sync();
    }
}

// ======================= fallback path (round-8, proven) =======================
#define OFF8_X0 0
#define OFF8_X1 65536
#define OFF8_M  131072
#define OFF8_HZ 163840
#define WS8_FLT 229376

__global__ __launch_bounds__(256) void zero8_kernel(float* __restrict__ p, int n)
{
    int i = blockIdx.x * 256 + threadIdx.x;
    if (i < n) p[i] = 0.0f;
}

__global__ __launch_bounds__(256) void combo8_kernel(
    const float* __restrict__ inputs, const float* __restrict__ wfm,
    const float* __restrict__ by,     const float* __restrict__ WyhT,
    const float* __restrict__ WyxT,   const float* __restrict__ WyfT,
    const float* __restrict__ AT,     const float* __restrict__ BT,
    const float* __restrict__ xin,    const float* __restrict__ m,
    const float* __restrict__ hz,     float* __restrict__ xout,
    float* __restrict__ out, int t)
{
    const int bid  = blockIdx.x;
    const int lane = threadIdx.x & 63;
    const int wv   = threadIdx.x >> 6;
    const int cg_  = bid & 7;
    const int grp  = bid >> 3;
    const bool is_x = grp < 16;
    const int rg   = grp & 15;
    const int c    = cg_ * 64 + lane;
    const int r0   = rg * 8 + wv * 2;

    if (is_x) {
        if (t >= TT - 1) return;
        const float* x0 = xin + r0 * RR;
        const float* x1 = x0 + RR;
        float a0 = 0.0f, a1 = 0.0f;
        #pragma unroll 16
        for (int k = 0; k < RR; ++k) {
            float w = AT[k * RR + c];
            a0 = fmaf(x0[k], w, a0);
            a1 = fmaf(x1[k], w, a1);
        }
        const float* i0 = inputs + (r0 * TT + (t + 1)) * DD;
        const float* i1 = i0 + TT * DD;
        const float* m0 = m + r0 * DD;
        const float* m1 = m0 + DD;
        float b0 = 0.0f, b1 = 0.0f;
        #pragma unroll 16
        for (int d = 0; d < DD; ++d) {
            float w  = BT[d * RR + c];
            float u0 = i0[d] + m0[d];
            float u1 = i1[d] + m1[d];
            b0 = fmaf(u0, w, b0);
            b1 = fmaf(u1, w, b1);
        }
        xout[r0 * RR + c]       = a0 + b0;
        xout[(r0 + 1) * RR + c] = a1 + b1;
    } else {
        if (t < 0) return;
        const float* h0 = (t == 0) ? (hz + r0 * UU) : (out + (r0 * TT + (t - 1)) * UU);
        const float* h1 = (t == 0) ? (h0 + UU)      : (h0 + TT * UU);
        const float* x0 = xin + r0 * RR;
        const float* x1 = x0 + RR;
        float accH0 = 0.0f, accH1 = 0.0f, accX0 = 0.0f, accX1 = 0.0f;
        #pragma unroll 8
        for (int k = 0; k < UU; ++k) {
            float wh = WyhT[k * UU + c];
            float wx = WyxT[k * UU + c];
            accH0 = fmaf(h0[k], wh, accH0);
            accH1 = fmaf(h1[k], wh, accH1);
            accX0 = fmaf(x0[k], wx, accX0);
            accX1 = fmaf(x1[k], wx, accX1);
        }
        const float* m0 = m + r0 * DD;
        const float* m1 = m0 + DD;
        float accF0 = 0.0f, accF1 = 0.0f;
        #pragma unroll 16
        for (int d = 0; d < DD; ++d) {
            float w  = WyfT[d * UU + c];
            float f0 = wfm[d] * m0[d];
            float f1 = wfm[d] * m1[d];
            accF0 = fmaf(f0, w, accF0);
            accF1 = fmaf(f1, w, accF1);
        }
        float z0 = ((accH0 + accX0) + accF0) + by[c];
        float z1 = ((accH1 + accX1) + accF1) + by[c];
        out[(r0 * TT + t) * UU + c]       = tanhf(z0);
        out[((r0 + 1) * TT + t) * UU + c] = tanhf(z1);
    }
}

__global__ __launch_bounds__(256) void m8_kernel(
    const float* __restrict__ CT, const float* __restrict__ x,
    float* __restrict__ m)
{
    const int bid  = blockIdx.x;
    const int lane = threadIdx.x & 63;
    const int wv   = threadIdx.x >> 6;
    const int cg_  = bid & 7;
    const int rg   = bid >> 3;
    const int row  = rg * 8 + wv * 2 + (lane >> 5);
    const int c    = cg_ * 32 + (lane & 31);
    const float* xr = x + row * RR;
    float acc = 0.0f;
    #pragma unroll 16
    for (int k = 0; k < RR; ++k)
        acc = fmaf(xr[k], CT[k * DD + c], acc);
    m[row * DD + c] = acc;
}

__global__ __launch_bounds__(64) void sentinel_kernel(float* __restrict__ out, float v)
{
    if (threadIdx.x == 0 && blockIdx.x == 0) out[0] = v;
}

extern "C" void kernel_launch(void* const* d_in, const int* in_sizes, int n_in,
                              void* d_out, int out_size, void* d_ws, size_t ws_size,
                              hipStream_t stream)
{
    const float* inputs = (const float*)d_in[0];
    const float* wfm    = (const float*)d_in[1];
    const float* WyhT   = (const float*)d_in[2];
    const float* WyxT   = (const float*)d_in[3];
    const float* WyfT   = (const float*)d_in[4];
    const float* by     = (const float*)d_in[5];
    const float* AT     = (const float*)d_in[6];
    const float* BT     = (const float*)d_in[7];
    const float* CT     = (const float*)d_in[8];
    float* out = (float*)d_out;
    float* ws  = (float*)d_ws;

    // Environment sentinels (absmax reveals code if triggered).
    double code = 0.0;
    static const int exp_sizes[9] = {8388608, 256, 262144, 262144, 131072,
                                     512, 262144, 131072, 131072};
    if (n_in != 9) {
        code = 3.0e6 + n_in;
    } else {
        for (int i = 0; i < 9; ++i)
            if (in_sizes[i] != exp_sizes[i]) { code = 2.0e6 + i * 1.0e4; break; }
    }
    if (code == 0.0 && out_size != BB * TT * UU)
        code = 4.0e6 + (double)(out_size / 10000);
    if (code == 0.0 && ws_size < (size_t)WS_NEED_BYTES)
        code = 1.0e6 + (double)(ws_size / 1024);
    if (code != 0.0) {
        sentinel_kernel<<<1, 64, 0, stream>>>(out, (float)code);
        return;
    }

    // ---- cooperative persistent kernel ----
    (void)hipFuncSetAttribute(reinterpret_cast<const void*>(ladder_coop),
                              hipFuncAttributeMaxDynamicSharedMemorySize,
                              LDS_BYTES);
    void* args[] = {
        (void*)&inputs, (void*)&wfm, (void*)&by, (void*)&WyhT, (void*)&WyxT,
        (void*)&WyfT, (void*)&AT, (void*)&BT, (void*)&CT, (void*)&ws, (void*)&out
    };
    hipError_t e = hipLaunchCooperativeKernel(
        reinterpret_cast<const void*>(ladder_coop),
        dim3(256), dim3(256), args, LDS_BYTES, stream);
    if (e == hipSuccess) return;

    // ---- deterministic fallback: proven round-8 launch sequence ----
    float* X0 = ws + OFF8_X0;
    float* X1 = ws + OFF8_X1;
    float* M  = ws + OFF8_M;
    float* HZ = ws + OFF8_HZ;
    zero8_kernel<<<(WS8_FLT + 255) / 256, 256, 0, stream>>>(ws, WS8_FLT);
    combo8_kernel<<<256, 256, 0, stream>>>(inputs, wfm, by, WyhT, WyxT, WyfT, AT, BT,
                                           X1, M, HZ, X0, out, -1);
    m8_kernel<<<128, 256, 0, stream>>>(CT, X0, M);
    for (int t = 0; t < TT - 1; ++t) {
        float* xc = (t & 1) ? X1 : X0;
        float* xn = (t & 1) ? X0 : X1;
        combo8_kernel<<<256, 256, 0, stream>>>(inputs, wfm, by, WyhT, WyxT, WyfT, AT, BT,
                                               xc, M, HZ, xn, out, t);
        m8_kernel<<<128, 256, 0, stream>>>(CT, xn, M);
    }
    combo8_kernel<<<256, 256, 0, stream>>>(inputs, wfm, by, WyhT, WyxT, WyfT, AT, BT,
                                           X1, M, HZ, X0, out, TT - 1);
}

// Round 10
// 17543.326 us; speedup vs baseline: 4.3991x; 4.3991x over previous
//
#include <hip/hip_runtime.h>
#include <math.h>

#define BB 128   // batch
#define TT 256   // time
#define DD 256   // input dims
#define UU 512   // units
#define RR 512   // ladder order

// ws layout (floats), row-major activations:
//   X0 [128][512] @ 0        x_j lives in X[j&1]
//   X1 [128][512] @ 65536
//   M  [128][256] @ 131072   m_t while combo(t) runs
//   HZ [128][512] @ 163840   zeros (h_{-1})
#define OFF_X0 0
#define OFF_X1 65536
#define OFF_M  131072
#define OFF_HZ 163840
#define WS_FLT 229376
#define WS_NEED_BYTES (WS_FLT * 4)

__global__ __launch_bounds__(256) void zero_kernel(float* __restrict__ p, int n)
{
    int i = blockIdx.x * 256 + threadIdx.x;
    if (i < n) p[i] = 0.0f;
}

// combo(t): 512 blocks x 256 threads, 1 output element per thread.
//   bid <  256 (h-part): h_t[row][c] = tanhf(((accH+accX)+accF)+by[c])   (t>=0)
//   bid >= 256 (x-part): x_{t+1}[row][c] = accA + accB                    (t<=254)
// Mapping: cg = bid&7 (XCD-aligned 64-col slice), rg = (bid&255)>>3 (0..31),
//          row = rg*4 + (tid>>6), c = cg*64 + (tid&63).
// Bitwise contract (= np reference, proven rounds 7-8): every dot is an
// ascending-k single-accumulator fmaf chain from 0.0f; u = inp+m (one add);
// f = wfm*m (one mul); x = accA+accB (one add); z = ((accH+accX)+accF)+by.
// Fusing independent chains / unrolling does not alter any chain's op order.
__global__ __launch_bounds__(256, 2) void combo_kernel(
    const float* __restrict__ inputs, const float* __restrict__ wfm,
    const float* __restrict__ by,     const float* __restrict__ WyhT,
    const float* __restrict__ WyxT,   const float* __restrict__ WyfT,
    const float* __restrict__ AT,     const float* __restrict__ BT,
    const float* __restrict__ xin,    // x_t
    const float* __restrict__ m,      // m_t
    const float* __restrict__ hz,     // zeros (h_{-1})
    float* __restrict__ xout,         // x_{t+1}
    float* __restrict__ out, int t)
{
    const int bid  = blockIdx.x;
    const int lane = threadIdx.x & 63;
    const int wv   = threadIdx.x >> 6;
    const bool is_h = bid < 256;
    const int b    = bid & 255;
    const int cg   = b & 7;
    const int rg   = b >> 3;
    const int row  = rg * 4 + wv;        // 0..127
    const int c    = cg * 64 + lane;     // 0..511

    if (is_h) {
        if (t < 0) return;
        const float* hr = (t == 0) ? (hz + row * UU)
                                   : (out + (row * TT + (t - 1)) * UU);
        const float* xr = xin + row * RR;
        float ah = 0.0f, ax = 0.0f;
        #pragma unroll 16
        for (int k = 0; k < UU; ++k) {
            float wh = WyhT[k * UU + c];
            float wx = WyxT[k * UU + c];
            ah = fmaf(hr[k], wh, ah);
            ax = fmaf(xr[k], wx, ax);
        }
        const float* mr = m + row * DD;
        float af = 0.0f;
        #pragma unroll 16
        for (int d = 0; d < DD; ++d) {
            float f = wfm[d] * mr[d];          // f = wfm*m_t (one round)
            af = fmaf(f, WyfT[d * UU + c], af);
        }
        float z = ((ah + ax) + af) + by[c];
        out[(row * TT + t) * UU + c] = tanhf(z);
    } else {
        if (t >= TT - 1) return;
        const float* xr = xin + row * RR;
        const float* ir = inputs + (row * TT + (t + 1)) * DD;
        const float* mr = m + row * DD;
        float a = 0.0f, bb = 0.0f;
        // Fused first 256 iters: accA(k) and accB(d=k) advance together
        // (independent chains; each keeps its own ascending order).
        #pragma unroll 16
        for (int k = 0; k < DD; ++k) {
            float wA = AT[k * RR + c];
            float wB = BT[k * RR + c];
            float u  = ir[k] + mr[k];          // u = inp_{t+1}+m_t (one round)
            a  = fmaf(xr[k], wA, a);
            bb = fmaf(u, wB, bb);
        }
        #pragma unroll 16
        for (int k = DD; k < RR; ++k)
            a = fmaf(xr[k], AT[k * RR + c], a);
        xout[row * RR + c] = a + bb;           // dot + dot, one add
    }
}

// m_t = x_t @ CT: 128 blocks x 256 threads, 1 output/thread.
// cg = bid&3 (64-col slice), rg = bid>>2, row = rg*4+wv, c = cg*64+lane.
__global__ __launch_bounds__(256, 2) void m_kernel(
    const float* __restrict__ CT, const float* __restrict__ x,
    float* __restrict__ m)
{
    const int bid  = blockIdx.x;
    const int lane = threadIdx.x & 63;
    const int wv   = threadIdx.x >> 6;
    const int cg   = bid & 3;
    const int rg   = bid >> 2;
    const int row  = rg * 4 + wv;        // 0..127
    const int c    = cg * 64 + lane;     // 0..255
    const float* xr = x + row * RR;
    float acc = 0.0f;
    #pragma unroll 32
    for (int k = 0; k < RR; ++k)
        acc = fmaf(xr[k], CT[k * DD + c], acc);
    m[row * DD + c] = acc;
}

__global__ __launch_bounds__(64) void sentinel_kernel(float* __restrict__ out, float v)
{
    if (threadIdx.x == 0 && blockIdx.x == 0) out[0] = v;
}

extern "C" void kernel_launch(void* const* d_in, const int* in_sizes, int n_in,
                              void* d_out, int out_size, void* d_ws, size_t ws_size,
                              hipStream_t stream)
{
    const float* inputs = (const float*)d_in[0];
    const float* wfm    = (const float*)d_in[1];
    const float* WyhT   = (const float*)d_in[2];
    const float* WyxT   = (const float*)d_in[3];
    const float* WyfT   = (const float*)d_in[4];
    const float* by     = (const float*)d_in[5];
    const float* AT     = (const float*)d_in[6];
    const float* BT     = (const float*)d_in[7];
    const float* CT     = (const float*)d_in[8];
    float* out = (float*)d_out;
    float* ws  = (float*)d_ws;

    // Environment sentinels (absmax reveals code if triggered).
    double code = 0.0;
    static const int exp_sizes[9] = {8388608, 256, 262144, 262144, 131072,
                                     512, 262144, 131072, 131072};
    if (n_in != 9) {
        code = 3.0e6 + n_in;
    } else {
        for (int i = 0; i < 9; ++i)
            if (in_sizes[i] != exp_sizes[i]) { code = 2.0e6 + i * 1.0e4; break; }
    }
    if (code == 0.0 && out_size != BB * TT * UU)
        code = 4.0e6 + (double)(out_size / 10000);
    if (code == 0.0 && ws_size < (size_t)WS_NEED_BYTES)
        code = 1.0e6 + (double)(ws_size / 1024);
    if (code != 0.0) {
        sentinel_kernel<<<1, 64, 0, stream>>>(out, (float)code);
        return;
    }

    float* X0 = ws + OFF_X0;
    float* X1 = ws + OFF_X1;
    float* M  = ws + OFF_M;
    float* HZ = ws + OFF_HZ;

    // Zero X1 (x_{-1}), M (m_{-1}), HZ (h_{-1}); X0 written before read.
    zero_kernel<<<(WS_FLT + 255) / 256, 256, 0, stream>>>(ws, WS_FLT);

    // Prologue: x_0 = 0@AT + (inp_0+0)@BT  (h-part skipped; zero chains bitwise-free)
    combo_kernel<<<512, 256, 0, stream>>>(inputs, wfm, by, WyhT, WyxT, WyfT, AT, BT,
                                          X1, M, HZ, X0, out, -1);
    m_kernel<<<128, 256, 0, stream>>>(CT, X0, M);   // m_0

    // t = 0..254: combo(t) = { h_t ; x_{t+1} }, then m_{t+1} = x_{t+1}@CT.
    for (int t = 0; t < TT - 1; ++t) {
        float* xc = (t & 1) ? X1 : X0;   // x_t
        float* xn = (t & 1) ? X0 : X1;   // x_{t+1}
        combo_kernel<<<512, 256, 0, stream>>>(inputs, wfm, by, WyhT, WyxT, WyfT, AT, BT,
                                              xc, M, HZ, xn, out, t);
        m_kernel<<<128, 256, 0, stream>>>(CT, xn, M);
    }
    // t = 255: h_255 only (x-part self-disables). x_255 lives in X1.
    combo_kernel<<<512, 256, 0, stream>>>(inputs, wfm, by, WyhT, WyxT, WyfT, AT, BT,
                                          X1, M, HZ, X0, out, TT - 1);
}